// Round 1
// baseline (1330.014 us; speedup 1.0000x reference)
//
#include <hip/hip_runtime.h>

#define N_NODES 100000
#define N_EDGES 3200000
#define N_GRAPHS 64
#define F 16

__global__ __launch_bounds__(256) void k_degree(const int* __restrict__ row,
                                                const int* __restrict__ col,
                                                int* __restrict__ deg,
                                                int* __restrict__ cnt, int E) {
    int i = blockIdx.x * blockDim.x + threadIdx.x;
    int stride = gridDim.x * blockDim.x;
    for (; i < E; i += stride) {
        atomicAdd(&deg[row[i]], 1);
        atomicAdd(&cnt[col[i]], 1);
    }
}

__global__ __launch_bounds__(256) void k_dinv(const int* __restrict__ deg,
                                              const int* __restrict__ cnt,
                                              float* __restrict__ dinv,
                                              float* __restrict__ invcnt, int N) {
    int i = blockIdx.x * blockDim.x + threadIdx.x;
    if (i >= N) return;
    int d = deg[i];
    dinv[i] = d > 0 ? rsqrtf((float)d) : 0.0f;
    int c = cnt[i];
    invcnt[i] = 1.0f / (float)(c > 1 ? c : 1);
}

// conv1 node transform: center = x@W1+b1, xj = x@W2   (3 -> 16)
// one thread per (node, feature)
__global__ __launch_bounds__(256) void k_node1(const float* __restrict__ x,
                                               const float* __restrict__ W1,
                                               const float* __restrict__ b1,
                                               const float* __restrict__ W2,
                                               float* __restrict__ center,
                                               float* __restrict__ xj, int N) {
    int t = blockIdx.x * blockDim.x + threadIdx.x;
    if (t >= N * F) return;
    int n = t >> 4, k = t & 15;
    float x0 = x[n * 3 + 0], x1 = x[n * 3 + 1], x2 = x[n * 3 + 2];
    center[t] = b1[k] + x0 * W1[0 * F + k] + x1 * W1[1 * F + k] + x2 * W1[2 * F + k];
    xj[t]     =         x0 * W2[0 * F + k] + x1 * W2[1 * F + k] + x2 * W2[2 * F + k];
}

// edge scatter: s[col] += dinv[row]*dinv[col] * xj[row]
// one thread per (edge, feature); 16 lanes share an edge
__global__ __launch_bounds__(256) void k_scatter(const int* __restrict__ row,
                                                 const int* __restrict__ col,
                                                 const float* __restrict__ dinv,
                                                 const float* __restrict__ xj,
                                                 float* __restrict__ s, int total) {
    int t = blockIdx.x * blockDim.x + threadIdx.x;
    int stride = gridDim.x * blockDim.x;
    for (; t < total; t += stride) {
        int e = t >> 4, k = t & 15;
        int r = row[e], c = col[e];
        float w = dinv[r] * dinv[c];
        atomicAdd(&s[c * F + k], w * xj[r * F + k]);
    }
}

// finalize conv1 (relu(center + s*invcnt)) then conv2 node transform (16->16).
// center/xj are read and overwritten in-place (each thread owns its row).
// s row is zeroed after reading so it is ready for the second scatter.
__global__ __launch_bounds__(256) void k_node2(float* center_io, float* s,
                                               const float* __restrict__ invcnt,
                                               const float* __restrict__ W1,
                                               const float* __restrict__ b1,
                                               const float* __restrict__ W2,
                                               float* xj_io, int N) {
    int n = blockIdx.x * blockDim.x + threadIdx.x;
    if (n >= N) return;
    float ic = invcnt[n];
    float h[F];
#pragma unroll
    for (int k = 0; k < F; ++k) {
        float v = center_io[n * F + k] + s[n * F + k] * ic;
        h[k] = v > 0.0f ? v : 0.0f;
        s[n * F + k] = 0.0f;
    }
#pragma unroll
    for (int k = 0; k < F; ++k) {
        float c2 = b1[k];
        float x2 = 0.0f;
#pragma unroll
        for (int i = 0; i < F; ++i) {
            c2 += h[i] * W1[i * F + k];
            x2 += h[i] * W2[i * F + k];
        }
        center_io[n * F + k] = c2;
        xj_io[n * F + k] = x2;
    }
}

// finalize conv2 + scatter-mean pooling into graphs
__global__ __launch_bounds__(256) void k_pool(const float* __restrict__ center,
                                              const float* __restrict__ s,
                                              const float* __restrict__ invcnt,
                                              const int* __restrict__ batch,
                                              float* __restrict__ gpool,
                                              int* __restrict__ gcnt, int N) {
    int t = blockIdx.x * blockDim.x + threadIdx.x;
    if (t >= N * F) return;
    int n = t >> 4, k = t & 15;
    float h = center[t] + s[t] * invcnt[n];
    h = h > 0.0f ? h : 0.0f;
    int b = batch[n];
    atomicAdd(&gpool[b * F + k], h);
    if (k == 0) atomicAdd(&gcnt[b], 1);
}

// g = gpool/max(gcnt,1); g = relu(g@l1W+l1b); out = g@l2W+l2b
__global__ __launch_bounds__(64) void k_mlp(const float* __restrict__ gpool,
                                            const int* __restrict__ gcnt,
                                            const float* __restrict__ l1W,
                                            const float* __restrict__ l1b,
                                            const float* __restrict__ l2W,
                                            const float* __restrict__ l2b,
                                            float* __restrict__ out) {
    int g = threadIdx.x;
    if (g >= N_GRAPHS) return;
    int c = gcnt[g];
    float ic = 1.0f / (float)(c > 1 ? c : 1);
    float v[F], h[F];
#pragma unroll
    for (int k = 0; k < F; ++k) v[k] = gpool[g * F + k] * ic;
#pragma unroll
    for (int k = 0; k < F; ++k) {
        float a = l1b[k];
#pragma unroll
        for (int i = 0; i < F; ++i) a += v[i] * l1W[i * F + k];
        h[k] = a > 0.0f ? a : 0.0f;
    }
#pragma unroll
    for (int j = 0; j < 2; ++j) {
        float a = l2b[j];
#pragma unroll
        for (int i = 0; i < F; ++i) a += h[i] * l2W[i * 2 + j];
        out[g * 2 + j] = a;
    }
}

extern "C" void kernel_launch(void* const* d_in, const int* in_sizes, int n_in,
                              void* d_out, int out_size, void* d_ws, size_t ws_size,
                              hipStream_t stream) {
    const float* x     = (const float*)d_in[0];
    const int*   ei    = (const int*)d_in[1];
    const int*   row   = ei;
    const int*   col   = ei + N_EDGES;
    const int*   batch = (const int*)d_in[2];
    const float* c1W1  = (const float*)d_in[3];
    const float* c1b1  = (const float*)d_in[4];
    const float* c1W2  = (const float*)d_in[5];
    const float* c2W1  = (const float*)d_in[6];
    const float* c2b1  = (const float*)d_in[7];
    const float* c2W2  = (const float*)d_in[8];
    const float* l1W   = (const float*)d_in[9];
    const float* l1b   = (const float*)d_in[10];
    const float* l2W   = (const float*)d_in[11];
    const float* l2b   = (const float*)d_in[12];
    float* out = (float*)d_out;

    // workspace layout
    int*   deg    = (int*)d_ws;                    // N ints
    int*   cnt    = deg + N_NODES;                 // N ints
    float* dinv   = (float*)(cnt + N_NODES);       // N floats
    float* invcnt = dinv + N_NODES;                // N floats
    float* center = invcnt + N_NODES;              // N*F floats
    float* xj     = center + N_NODES * F;          // N*F floats
    float* s      = xj + N_NODES * F;              // N*F floats
    float* gpool  = s + N_NODES * F;               // G*F floats
    int*   gcnt   = (int*)(gpool + N_GRAPHS * F);  // G ints

    hipMemsetAsync(deg, 0, 2 * N_NODES * sizeof(int), stream);
    hipMemsetAsync(s, 0, (size_t)N_NODES * F * sizeof(float), stream);
    hipMemsetAsync(gpool, 0, N_GRAPHS * F * sizeof(float) + N_GRAPHS * sizeof(int), stream);

    k_degree<<<2048, 256, 0, stream>>>(row, col, deg, cnt, N_EDGES);
    k_dinv<<<(N_NODES + 255) / 256, 256, 0, stream>>>(deg, cnt, dinv, invcnt, N_NODES);
    k_node1<<<(N_NODES * F + 255) / 256, 256, 0, stream>>>(x, c1W1, c1b1, c1W2, center, xj, N_NODES);
    k_scatter<<<8192, 256, 0, stream>>>(row, col, dinv, xj, s, N_EDGES * F);
    k_node2<<<(N_NODES + 255) / 256, 256, 0, stream>>>(center, s, invcnt, c2W1, c2b1, c2W2, xj, N_NODES);
    k_scatter<<<8192, 256, 0, stream>>>(row, col, dinv, xj, s, N_EDGES * F);
    k_pool<<<(N_NODES * F + 255) / 256, 256, 0, stream>>>(center, s, invcnt, batch, gpool, gcnt, N_NODES);
    k_mlp<<<1, 64, 0, stream>>>(gpool, gcnt, l1W, l1b, l2W, l2b, out);
}

// Round 2
// 803.754 us; speedup vs baseline: 1.6548x; 1.6548x over previous
//
#include <hip/hip_runtime.h>

#define N_NODES 100000
#define N_EDGES 3200000
#define N_GRAPHS 64
#define F 16

#define SCAN_ELEMS 1024
#define NB ((N_NODES + SCAN_ELEMS - 1) / SCAN_ELEMS)   // 98
#define POOL_CHUNK 64

__global__ __launch_bounds__(256) void k_degree(const int* __restrict__ row,
                                                const int* __restrict__ col,
                                                int* __restrict__ deg,
                                                int* __restrict__ cnt) {
    int i = blockIdx.x * blockDim.x + threadIdx.x;
    int stride = gridDim.x * blockDim.x;
    for (; i < N_EDGES; i += stride) {
        atomicAdd(&deg[row[i]], 1);
        atomicAdd(&cnt[col[i]], 1);
    }
}

__global__ __launch_bounds__(256) void k_dinv(const int* __restrict__ deg,
                                              const int* __restrict__ cnt,
                                              float* __restrict__ dinv,
                                              float* __restrict__ invcnt) {
    int i = blockIdx.x * blockDim.x + threadIdx.x;
    if (i >= N_NODES) return;
    int d = deg[i];
    dinv[i] = d > 0 ? rsqrtf((float)d) : 0.0f;
    int c = cnt[i];
    invcnt[i] = 1.0f / (float)(c > 1 ? c : 1);
}

// ---- block-scan to build rowptr (exclusive prefix over cnt) ----
__global__ __launch_bounds__(256) void k_scan_part(const int* __restrict__ cnt,
                                                   int* __restrict__ bsum) {
    __shared__ int sd[256];
    int t = threadIdx.x;
    int base = blockIdx.x * SCAN_ELEMS + t * 4;
    int s = 0;
#pragma unroll
    for (int i = 0; i < 4; ++i) { int idx = base + i; if (idx < N_NODES) s += cnt[idx]; }
    sd[t] = s; __syncthreads();
    for (int off = 128; off > 0; off >>= 1) {
        if (t < off) sd[t] += sd[t + off];
        __syncthreads();
    }
    if (t == 0) bsum[blockIdx.x] = sd[0];
}

__global__ __launch_bounds__(128) void k_scan_bsum(const int* __restrict__ bsum,
                                                   int* __restrict__ boff) {
    __shared__ int sd[128];
    int t = threadIdx.x;
    sd[t] = (t < NB) ? bsum[t] : 0;
    __syncthreads();
    for (int off = 1; off < 128; off <<= 1) {
        int a = (t >= off) ? sd[t - off] : 0;
        __syncthreads();
        sd[t] += a;
        __syncthreads();
    }
    if (t < NB) boff[t] = (t == 0) ? 0 : sd[t - 1];
}

__global__ __launch_bounds__(256) void k_scan_write(const int* __restrict__ cnt,
                                                    const int* __restrict__ boff,
                                                    int* __restrict__ rowptr) {
    __shared__ int ts[256];
    int t = threadIdx.x;
    int base = blockIdx.x * SCAN_ELEMS + t * 4;
    int v0 = 0, v1 = 0, v2 = 0, v3 = 0;
    if (base + 0 < N_NODES) v0 = cnt[base + 0];
    if (base + 1 < N_NODES) v1 = cnt[base + 1];
    if (base + 2 < N_NODES) v2 = cnt[base + 2];
    if (base + 3 < N_NODES) v3 = cnt[base + 3];
    int mysum = v0 + v1 + v2 + v3;
    ts[t] = mysum;
    __syncthreads();
    for (int off = 1; off < 256; off <<= 1) {
        int a = (t >= off) ? ts[t - off] : 0;
        __syncthreads();
        ts[t] += a;
        __syncthreads();
    }
    int run = boff[blockIdx.x] + ts[t] - mysum;
    if (base + 0 < N_NODES) { rowptr[base + 0] = run; run += v0; }
    if (base + 1 < N_NODES) { rowptr[base + 1] = run; run += v1; }
    if (base + 2 < N_NODES) { rowptr[base + 2] = run; run += v2; }
    if (base + 3 < N_NODES) { rowptr[base + 3] = run; run += v3; }
}

__global__ __launch_bounds__(256) void k_fill_init(const int* __restrict__ rowptr,
                                                   int* __restrict__ fillpos) {
    int i = blockIdx.x * blockDim.x + threadIdx.x;
    if (i == 0) fillpos[N_NODES] = 0; // unused slot, keep deterministic
    if (i < N_NODES) fillpos[i] = rowptr[i];
}

__global__ __launch_bounds__(256) void k_set_rowptr_end(int* __restrict__ rowptr) {
    if (blockIdx.x == 0 && threadIdx.x == 0) rowptr[N_NODES] = N_EDGES;
}

__global__ __launch_bounds__(256) void k_fill(const int* __restrict__ row,
                                              const int* __restrict__ col,
                                              int* __restrict__ fillpos,
                                              int* __restrict__ srcarr) {
    int e = blockIdx.x * blockDim.x + threadIdx.x;
    int stride = gridDim.x * blockDim.x;
    for (; e < N_EDGES; e += stride) {
        int c = col[e];
        int slot = atomicAdd(&fillpos[c], 1);
        srcarr[slot] = row[e];
    }
}

// conv1 node transform: center = x@W1+b1, xj = x@W2   (3 -> 16)
__global__ __launch_bounds__(256) void k_node1(const float* __restrict__ x,
                                               const float* __restrict__ W1,
                                               const float* __restrict__ b1,
                                               const float* __restrict__ W2,
                                               float* __restrict__ center,
                                               float* __restrict__ xj) {
    int t = blockIdx.x * blockDim.x + threadIdx.x;
    if (t >= N_NODES * F) return;
    int n = t >> 4, k = t & 15;
    float x0 = x[n * 3 + 0], x1 = x[n * 3 + 1], x2 = x[n * 3 + 2];
    center[t] = b1[k] + x0 * W1[0 * F + k] + x1 * W1[1 * F + k] + x2 * W1[2 * F + k];
    xj[t]     =         x0 * W2[0 * F + k] + x1 * W2[1 * F + k] + x2 * W2[2 * F + k];
}

// atomic-free pull gather: s[n,k] = dinv[n]*invcnt[n] * sum_{e: col=n} dinv[src]*xj[src,k]
__global__ __launch_bounds__(256) void k_gather(const int* __restrict__ rowptr,
                                                const int* __restrict__ srcarr,
                                                const float* __restrict__ dinv,
                                                const float* __restrict__ invcnt,
                                                const float* __restrict__ xj,
                                                float* __restrict__ s_out) {
    int t = blockIdx.x * blockDim.x + threadIdx.x;
    if (t >= N_NODES * F) return;
    int n = t >> 4, k = t & 15;
    int beg = rowptr[n], end = rowptr[n + 1];
    float acc = 0.0f;
    for (int j = beg; j < end; ++j) {
        int r = srcarr[j];
        acc += dinv[r] * xj[r * F + k];
    }
    s_out[t] = acc * dinv[n] * invcnt[n];
}

// fallback: atomic edge scatter (one thread per edge-feature)
__global__ __launch_bounds__(256) void k_scatter(const int* __restrict__ row,
                                                 const int* __restrict__ col,
                                                 const float* __restrict__ dinv,
                                                 const float* __restrict__ xj,
                                                 float* __restrict__ s) {
    int t = blockIdx.x * blockDim.x + threadIdx.x;
    int stride = gridDim.x * blockDim.x;
    for (; t < N_EDGES * F; t += stride) {
        int e = t >> 4, k = t & 15;
        int r = row[e], c = col[e];
        float w = dinv[r] * dinv[c];
        atomicAdd(&s[c * F + k], w * xj[r * F + k]);
    }
}

// finalize conv1 (relu(center + s[*ic])) then conv2 node transform (16->16)
__global__ __launch_bounds__(256) void k_node2(float* center_io, float* s,
                                               const float* __restrict__ icmul,
                                               const float* __restrict__ W1,
                                               const float* __restrict__ b1,
                                               const float* __restrict__ W2,
                                               float* xj_io, int zero_s) {
    int n = blockIdx.x * blockDim.x + threadIdx.x;
    if (n >= N_NODES) return;
    float ic = icmul ? icmul[n] : 1.0f;
    float h[F];
#pragma unroll
    for (int k = 0; k < F; ++k) {
        float v = center_io[n * F + k] + s[n * F + k] * ic;
        h[k] = v > 0.0f ? v : 0.0f;
        if (zero_s) s[n * F + k] = 0.0f;
    }
#pragma unroll
    for (int k = 0; k < F; ++k) {
        float c2 = b1[k];
        float x2 = 0.0f;
#pragma unroll
        for (int i = 0; i < F; ++i) {
            c2 += h[i] * W1[i * F + k];
            x2 += h[i] * W2[i * F + k];
        }
        center_io[n * F + k] = c2;
        xj_io[n * F + k] = x2;
    }
}

// run-length pooling over sorted batch: ~1-2 atomics per 64-node chunk per feature
__global__ __launch_bounds__(256) void k_pool(const float* __restrict__ center,
                                              const float* __restrict__ s,
                                              const float* __restrict__ icmul,
                                              const int* __restrict__ batch,
                                              float* __restrict__ gpool,
                                              int* __restrict__ gcnt) {
    int t = blockIdx.x * blockDim.x + threadIdx.x;
    int gid = t >> 4, k = t & 15;
    int n0 = gid * POOL_CHUNK;
    if (n0 >= N_NODES) return;
    int n1 = n0 + POOL_CHUNK; if (n1 > N_NODES) n1 = N_NODES;
    int bcur = batch[n0];
    float acc = 0.0f; int run = 0;
    for (int n = n0; n < n1; ++n) {
        int b = batch[n];
        if (b != bcur) {
            atomicAdd(&gpool[bcur * F + k], acc);
            if (k == 0) atomicAdd(&gcnt[bcur], run);
            acc = 0.0f; run = 0; bcur = b;
        }
        float ic = icmul ? icmul[n] : 1.0f;
        float h = center[n * F + k] + s[n * F + k] * ic;
        acc += h > 0.0f ? h : 0.0f;
        ++run;
    }
    atomicAdd(&gpool[bcur * F + k], acc);
    if (k == 0) atomicAdd(&gcnt[bcur], run);
}

__global__ __launch_bounds__(64) void k_mlp(const float* __restrict__ gpool,
                                            const int* __restrict__ gcnt,
                                            const float* __restrict__ l1W,
                                            const float* __restrict__ l1b,
                                            const float* __restrict__ l2W,
                                            const float* __restrict__ l2b,
                                            float* __restrict__ out) {
    int g = threadIdx.x;
    if (g >= N_GRAPHS) return;
    int c = gcnt[g];
    float ic = 1.0f / (float)(c > 1 ? c : 1);
    float v[F], h[F];
#pragma unroll
    for (int k = 0; k < F; ++k) v[k] = gpool[g * F + k] * ic;
#pragma unroll
    for (int k = 0; k < F; ++k) {
        float a = l1b[k];
#pragma unroll
        for (int i = 0; i < F; ++i) a += v[i] * l1W[i * F + k];
        h[k] = a > 0.0f ? a : 0.0f;
    }
#pragma unroll
    for (int j = 0; j < 2; ++j) {
        float a = l2b[j];
#pragma unroll
        for (int i = 0; i < F; ++i) a += h[i] * l2W[i * 2 + j];
        out[g * 2 + j] = a;
    }
}

extern "C" void kernel_launch(void* const* d_in, const int* in_sizes, int n_in,
                              void* d_out, int out_size, void* d_ws, size_t ws_size,
                              hipStream_t stream) {
    const float* x     = (const float*)d_in[0];
    const int*   ei    = (const int*)d_in[1];
    const int*   row   = ei;
    const int*   col   = ei + N_EDGES;
    const int*   batch = (const int*)d_in[2];
    const float* c1W1  = (const float*)d_in[3];
    const float* c1b1  = (const float*)d_in[4];
    const float* c1W2  = (const float*)d_in[5];
    const float* c2W1  = (const float*)d_in[6];
    const float* c2b1  = (const float*)d_in[7];
    const float* c2W2  = (const float*)d_in[8];
    const float* l1W   = (const float*)d_in[9];
    const float* l1b   = (const float*)d_in[10];
    const float* l2W   = (const float*)d_in[11];
    const float* l2b   = (const float*)d_in[12];
    float* out = (float*)d_out;

    // arena allocation (256B aligned each)
    char* p = (char*)d_ws;
    auto alloc = [&p](size_t bytes) -> void* {
        void* r = (void*)p;
        p += (bytes + 255) & ~(size_t)255;
        return r;
    };
    int*   deg    = (int*)  alloc(N_NODES * 4);
    int*   cnt    = (int*)  alloc(N_NODES * 4);
    float* dinv   = (float*)alloc(N_NODES * 4);
    float* invcnt = (float*)alloc(N_NODES * 4);
    float* center = (float*)alloc((size_t)N_NODES * F * 4);
    float* xj     = (float*)alloc((size_t)N_NODES * F * 4);
    float* s      = (float*)alloc((size_t)N_NODES * F * 4);
    float* gpool  = (float*)alloc(N_GRAPHS * F * 4);
    int*   gcnt   = (int*)  alloc(N_GRAPHS * 4);
    // CSR extras (allocated last so the base layout stands alone)
    int*   rowptr  = (int*)alloc((size_t)(N_NODES + 1) * 4);
    int*   fillpos = (int*)alloc((size_t)(N_NODES + 1) * 4);
    int*   srcarr  = (int*)alloc((size_t)N_EDGES * 4);
    int*   bsum    = (int*)alloc(128 * 4);
    int*   boff    = (int*)alloc(128 * 4);
    size_t needed_csr = (size_t)(p - (char*)d_ws);
    bool use_csr = ws_size >= needed_csr;

    hipMemsetAsync(deg, 0, N_NODES * 4, stream);
    hipMemsetAsync(cnt, 0, N_NODES * 4, stream);
    hipMemsetAsync(gpool, 0, N_GRAPHS * F * 4, stream);
    hipMemsetAsync(gcnt, 0, N_GRAPHS * 4, stream);

    k_degree<<<2048, 256, 0, stream>>>(row, col, deg, cnt);
    k_dinv<<<(N_NODES + 255) / 256, 256, 0, stream>>>(deg, cnt, dinv, invcnt);
    k_node1<<<(N_NODES * F + 255) / 256, 256, 0, stream>>>(x, c1W1, c1b1, c1W2, center, xj);

    if (use_csr) {
        k_scan_part<<<NB, 256, 0, stream>>>(cnt, bsum);
        k_scan_bsum<<<1, 128, 0, stream>>>(bsum, boff);
        k_scan_write<<<NB, 256, 0, stream>>>(cnt, boff, rowptr);
        k_set_rowptr_end<<<1, 64, 0, stream>>>(rowptr);
        k_fill_init<<<(N_NODES + 255) / 256, 256, 0, stream>>>(rowptr, fillpos);
        k_fill<<<4096, 256, 0, stream>>>(row, col, fillpos, srcarr);

        k_gather<<<(N_NODES * F + 255) / 256, 256, 0, stream>>>(rowptr, srcarr, dinv, invcnt, xj, s);
        k_node2<<<(N_NODES + 255) / 256, 256, 0, stream>>>(center, s, nullptr, c2W1, c2b1, c2W2, xj, 0);
        k_gather<<<(N_NODES * F + 255) / 256, 256, 0, stream>>>(rowptr, srcarr, dinv, invcnt, xj, s);
        k_pool<<<((N_NODES + POOL_CHUNK - 1) / POOL_CHUNK * 16 + 255) / 256, 256, 0, stream>>>(
            center, s, nullptr, batch, gpool, gcnt);
    } else {
        hipMemsetAsync(s, 0, (size_t)N_NODES * F * 4, stream);
        k_scatter<<<8192, 256, 0, stream>>>(row, col, dinv, xj, s);
        k_node2<<<(N_NODES + 255) / 256, 256, 0, stream>>>(center, s, invcnt, c2W1, c2b1, c2W2, xj, 1);
        k_scatter<<<8192, 256, 0, stream>>>(row, col, dinv, xj, s);
        k_pool<<<((N_NODES + POOL_CHUNK - 1) / POOL_CHUNK * 16 + 255) / 256, 256, 0, stream>>>(
            center, s, invcnt, batch, gpool, gcnt);
    }
    k_mlp<<<1, 64, 0, stream>>>(gpool, gcnt, l1W, l1b, l2W, l2b, out);
}